// Round 2
// baseline (41.853 us; speedup 1.0000x reference)
//
#include <hip/hip_runtime.h>

#define GRID_H 128
#define GRID_W 128
#define N_POS  8192
#define NTHREADS 1024
#define EPS_F  1e-12f

__global__ __launch_bounds__(NTHREADS) void MazeCollision_kernel(
    const float* __restrict__ pos,   // [N_POS, 2]
    const float* __restrict__ maze,  // [GRID_H, GRID_W]
    const float* __restrict__ rad_p, // [1]
    float* __restrict__ out)         // [1]
{
    __shared__ float smaze[GRID_H * GRID_W];  // 64 KiB LDS
    const int t = threadIdx.x;

    // Cooperative maze -> LDS staging: 4 x float4 per thread, coalesced.
    {
        const float4* m4 = (const float4*)maze;
        float4* s4 = (float4*)smaze;
        #pragma unroll
        for (int k = 0; k < (GRID_H * GRID_W / 4) / NTHREADS; ++k)
            s4[t + k * NTHREADS] = m4[t + k * NTHREADS];
    }
    const float rad = rad_p[0];
    __syncthreads();

    float acc = 0.0f;
    const float2* p2 = (const float2*)pos;
    #pragma unroll
    for (int k = 0; k < N_POS / NTHREADS; ++k) {
        const float2 xy = p2[t + k * NTHREADS];
        const float x = xy.x, y = xy.y;
        // window of cells whose centers (i+0.5, j+0.5) can be within rad;
        // floor/ceil padding keeps exact-boundary cells (contribution 0) safe.
        const int ilo = max(0, (int)floorf(x - 0.5f - rad));
        const int ihi = min(GRID_H - 1, (int)ceilf(x - 0.5f + rad));
        const int jlo = max(0, (int)floorf(y - 0.5f - rad));
        const int jhi = min(GRID_W - 1, (int)ceilf(y - 0.5f + rad));
        for (int i = ilo; i <= ihi; ++i) {
            const float dx = x - ((float)i + 0.5f);
            const float dx2 = dx * dx;
            const float* row = &smaze[i * GRID_W];
            for (int j = jlo; j <= jhi; ++j) {
                const float dy = y - ((float)j + 0.5f);
                const float d = sqrtf(fmaxf(dx2 + dy * dy, EPS_F));
                acc += fmaxf(rad - d, 0.0f) * row[j];
            }
        }
    }

    // 64-lane wave reduction
    #pragma unroll
    for (int off = 32; off > 0; off >>= 1)
        acc += __shfl_down(acc, off, 64);

    __shared__ float wsum[NTHREADS / 64];  // 16 wave partials
    const int lane = t & 63, wave = t >> 6;
    if (lane == 0) wsum[wave] = acc;
    __syncthreads();

    if (t < 16) {
        float v = wsum[t];
        #pragma unroll
        for (int off = 8; off > 0; off >>= 1)
            v += __shfl_down(v, off, 64);
        if (t == 0) out[0] = v;  // deterministic plain store; no memset needed
    }
}

extern "C" void kernel_launch(void* const* d_in, const int* in_sizes, int n_in,
                              void* d_out, int out_size, void* d_ws, size_t ws_size,
                              hipStream_t stream) {
    const float* pos  = (const float*)d_in[0];
    const float* maze = (const float*)d_in[1];
    const float* rad  = (const float*)d_in[2];
    float* out = (float*)d_out;

    MazeCollision_kernel<<<1, NTHREADS, 0, stream>>>(pos, maze, rad, out);
}

// Round 3
// 11.883 us; speedup vs baseline: 3.5220x; 3.5220x over previous
//
#include <hip/hip_runtime.h>

#define GRID_H 128
#define GRID_W 128
#define N_POS  8192
#define NBLOCKS 8
#define NTHREADS 1024
#define EPS_F  1e-12f
#define MAGIC  0x5CA1AB1Eu

__global__ __launch_bounds__(NTHREADS) void MazeCollision_kernel(
    const float* __restrict__ pos,   // [N_POS, 2]
    const float* __restrict__ maze,  // [GRID_H, GRID_W]
    const float* __restrict__ rad_p, // [1]
    float* __restrict__ out,         // [1]
    float* __restrict__ vals,        // d_ws + 0      : 8 block partials
    unsigned int* __restrict__ flags)// d_ws + 256 B  : 8 ready flags
{
    const int t = threadIdx.x;
    const int bid = blockIdx.x;
    const float rad = rad_p[0];

    const int gid = bid * NTHREADS + t;          // exactly N_POS threads
    const float2 xy = ((const float2*)pos)[gid];
    const float x = xy.x, y = xy.y;

    float acc = 0.0f;
    if (rad <= 1.5f) {
        // Fixed 4x4 window {floor(x)-1..+2} x {floor(y)-1..+2}: any center
        // outside it is >= 1.5 away => relu(rad-d)=0 for rad<=1.5.
        const int i0 = (int)floorf(x) - 1;
        const int j0 = (int)floorf(y) - 1;
        float dy2[4], colm[4];
        int jc[4];
        #pragma unroll
        for (int c = 0; c < 4; ++c) {
            const int j = j0 + c;
            const float dy = y - ((float)j + 0.5f);
            dy2[c] = dy * dy;
            colm[c] = ((unsigned)j < GRID_W) ? 1.0f : 0.0f;
            jc[c] = min(max(j, 0), GRID_W - 1);
        }
        #pragma unroll
        for (int r = 0; r < 4; ++r) {
            const int i = i0 + r;
            const float rowm = ((unsigned)i < GRID_H) ? 1.0f : 0.0f;
            const int ic = min(max(i, 0), GRID_H - 1);
            const float dx = x - ((float)i + 0.5f);
            const float dx2 = dx * dx;
            const int rowbase = ic * GRID_W;
            #pragma unroll
            for (int c = 0; c < 4; ++c) {
                const float occ = maze[rowbase + jc[c]];        // L1/L2 hit
                const float d = __builtin_amdgcn_sqrtf(fmaxf(dx2 + dy2[c], EPS_F));
                const float pen = fmaxf(rad - d, 0.0f);
                acc += pen * occ * (rowm * colm[c]);            // mask OOB
            }
        }
    } else {
        // General-radius fallback (not exercised at rad = 1.5).
        const int ilo = max(0, (int)floorf(x - 0.5f - rad));
        const int ihi = min(GRID_H - 1, (int)ceilf(x - 0.5f + rad));
        const int jlo = max(0, (int)floorf(y - 0.5f - rad));
        const int jhi = min(GRID_W - 1, (int)ceilf(y - 0.5f + rad));
        for (int i = ilo; i <= ihi; ++i) {
            const float dx = x - ((float)i + 0.5f);
            const float dx2 = dx * dx;
            for (int j = jlo; j <= jhi; ++j) {
                const float dyv = y - ((float)j + 0.5f);
                const float d = sqrtf(fmaxf(dx2 + dyv * dyv, EPS_F));
                acc += fmaxf(rad - d, 0.0f) * maze[i * GRID_W + j];
            }
        }
    }

    // wave (64-lane) reduction
    #pragma unroll
    for (int off = 32; off > 0; off >>= 1)
        acc += __shfl_down(acc, off, 64);

    __shared__ float wsum[NTHREADS / 64];   // 16 wave partials
    if ((t & 63) == 0) wsum[t >> 6] = acc;
    __syncthreads();

    if (t < NTHREADS / 64) {                // 16 lanes of wave 0
        float v = wsum[t];
        #pragma unroll
        for (int off = 8; off > 0; off >>= 1)
            v += __shfl_down(v, off, 64);   // lane 0 = block sum

        if (bid != 0) {
            if (t == 0) {
                // value first (relaxed), then flag with release: agent scope
                __hip_atomic_store(&vals[bid], v, __ATOMIC_RELAXED, __HIP_MEMORY_SCOPE_AGENT);
                __hip_atomic_store(&flags[bid], MAGIC, __ATOMIC_RELEASE, __HIP_MEMORY_SCOPE_AGENT);
            }
        } else {
            // block 0 is the consumer: lane 0 = own partial, lanes 1..7 gather
            float g = 0.0f;
            if (t == 0) g = v;
            if (t >= 1 && t < NBLOCKS) {
                while (__hip_atomic_load(&flags[t], __ATOMIC_ACQUIRE, __HIP_MEMORY_SCOPE_AGENT) != MAGIC) {}
                g = __hip_atomic_load(&vals[t], __ATOMIC_RELAXED, __HIP_MEMORY_SCOPE_AGENT);
                // reset for the next replay (first call sees 0xAA poison != MAGIC)
                __hip_atomic_store(&flags[t], 0u, __ATOMIC_RELAXED, __HIP_MEMORY_SCOPE_AGENT);
            }
            #pragma unroll
            for (int off = 4; off > 0; off >>= 1)
                g += __shfl_down(g, off, 64);
            if (t == 0) out[0] = g;         // deterministic plain store
        }
    }
}

extern "C" void kernel_launch(void* const* d_in, const int* in_sizes, int n_in,
                              void* d_out, int out_size, void* d_ws, size_t ws_size,
                              hipStream_t stream) {
    const float* pos  = (const float*)d_in[0];
    const float* maze = (const float*)d_in[1];
    const float* rad  = (const float*)d_in[2];
    float* out = (float*)d_out;
    float* vals = (float*)d_ws;
    unsigned int* flags = (unsigned int*)((char*)d_ws + 256);

    MazeCollision_kernel<<<NBLOCKS, NTHREADS, 0, stream>>>(pos, maze, rad, out, vals, flags);
}